// Round 1
// baseline (563.711 us; speedup 1.0000x reference)
//
#include <hip/hip_runtime.h>
#include <hip/hip_bf16.h>

// Problem: out[b,s,o] = sum_d WHT(x)[b,s,d] * W[o,d] + bias[o]
// x: (4,2048,4096) fp32, W: (4096,4096) fp32, b: (4096,) fp32, out fp32.
// M = 8192 rows, K = 4096, N = 4096. GEMM is B^T layout (W rows k-contiguous).

#define D_DIM 4096
#define M_ROWS 8192

typedef float f32x4 __attribute__((ext_vector_type(4)));
typedef __bf16 bf16x8 __attribute__((ext_vector_type(8)));

__device__ __forceinline__ unsigned short f2bf(float f) {
  // round-to-nearest-even fp32 -> bf16 (inputs are finite, no NaN path needed)
  unsigned int u = __float_as_uint(f);
  return (unsigned short)((u + 0x7fffu + ((u >> 16) & 1u)) >> 16);
}

__device__ __forceinline__ void async16(const void* g, void* l) {
  __builtin_amdgcn_global_load_lds(
      (const __attribute__((address_space(1))) unsigned int*)g,
      (__attribute__((address_space(3))) unsigned int*)l, 16, 0, 0);
}

// ---------------------------------------------------------------------------
// Kernel 1: per-row 4096-point Walsh-Hadamard transform (normalized), fp32 in,
// bf16 out. 16x16x16 Kronecker split: index i = a*256 + b*16 + c.
// Phase A: butterflies on a (reg), Phase B: on b (reg), Phase C: on c (reg).
// Only 2 syncthreads; LDS padded so hot reads are <=2-way bank conflicts.
// ---------------------------------------------------------------------------
#define WHT_AS 280  // a-stride in floats (280 mod 32 == 24)
#define WHT_BS 17   // b-stride in floats

__global__ __launch_bounds__(256) void wht_cast_rows(
    const float* __restrict__ X, unsigned short* __restrict__ Y) {
  __shared__ float s[16 * WHT_AS];  // 17920 B
  const int row = blockIdx.x;
  const float* xr = X + (size_t)row * D_DIM;
  const int t = threadIdx.x;
  float v[16];

  // Phase A: thread t owns i = a*256 + t for a = 0..15 (coalesced loads)
#pragma unroll
  for (int a = 0; a < 16; ++a) v[a] = xr[a * 256 + t];
#pragma unroll
  for (int h = 1; h < 16; h <<= 1) {
#pragma unroll
    for (int i = 0; i < 16; ++i) {
      if ((i & h) == 0) {
        float p = v[i], q = v[i + h];
        v[i] = p + q;
        v[i + h] = p - q;
      }
    }
  }
  {
    const int base = (t >> 4) * WHT_BS + (t & 15);  // b*BS + c
#pragma unroll
    for (int a = 0; a < 16; ++a) s[a * WHT_AS + base] = v[a];
  }
  __syncthreads();

  // Phase B: thread t = a*16 + c owns all b
  {
    const int base = (t >> 4) * WHT_AS + (t & 15);
#pragma unroll
    for (int b = 0; b < 16; ++b) v[b] = s[base + b * WHT_BS];
#pragma unroll
    for (int h = 1; h < 16; h <<= 1) {
#pragma unroll
      for (int i = 0; i < 16; ++i) {
        if ((i & h) == 0) {
          float p = v[i], q = v[i + h];
          v[i] = p + q;
          v[i + h] = p - q;
        }
      }
    }
#pragma unroll
    for (int b = 0; b < 16; ++b) s[base + b * WHT_BS] = v[b];
  }
  __syncthreads();

  // Phase C: thread t = a*16 + b owns all c; scale, cast, coalesced 32B store
  {
    const int base = (t >> 4) * WHT_AS + (t & 15) * WHT_BS;
#pragma unroll
    for (int c = 0; c < 16; ++c) v[c] = s[base + c];
#pragma unroll
    for (int h = 1; h < 16; h <<= 1) {
#pragma unroll
      for (int i = 0; i < 16; ++i) {
        if ((i & h) == 0) {
          float p = v[i], q = v[i + h];
          v[i] = p + q;
          v[i + h] = p - q;
        }
      }
    }
    union {
      unsigned short us[16];
      uint4 q4[2];
    } pk;
#pragma unroll
    for (int c = 0; c < 16; ++c) pk.us[c] = f2bf(v[c] * 0.015625f);  // 1/sqrt(4096)
    uint4* dst =
        (uint4*)(Y + (size_t)row * D_DIM + (t >> 4) * 256 + (t & 15) * 16);
    dst[0] = pk.q4[0];
    dst[1] = pk.q4[1];
  }
}

// ---------------------------------------------------------------------------
// Kernel 2: W fp32 -> bf16 cast (8 elems/thread, float4 in, uint4 out)
// ---------------------------------------------------------------------------
__global__ __launch_bounds__(256) void cast_w(const float* __restrict__ W,
                                              unsigned short* __restrict__ Wb) {
  const size_t i = ((size_t)blockIdx.x * 256 + threadIdx.x) * 8;
  const float4* p = (const float4*)(W + i);
  float4 f0 = p[0], f1 = p[1];
  union {
    unsigned short us[8];
    uint4 q;
  } pk;
  pk.us[0] = f2bf(f0.x);
  pk.us[1] = f2bf(f0.y);
  pk.us[2] = f2bf(f0.z);
  pk.us[3] = f2bf(f0.w);
  pk.us[4] = f2bf(f1.x);
  pk.us[5] = f2bf(f1.y);
  pk.us[6] = f2bf(f1.z);
  pk.us[7] = f2bf(f1.w);
  *(uint4*)(Wb + i) = pk.q;
}

// ---------------------------------------------------------------------------
// Kernel 3: bf16 GEMM, B^T layout, bias epilogue. m97 recipe:
// 128x128 tile, BK=32, 4 waves (2x2), 4x4 16x16x32 MFMA per wave,
// global_load_lds width-16 staging, 2-barrier K-loop.
// ---------------------------------------------------------------------------
__global__ __launch_bounds__(256) void gemm_bt_bias(
    const unsigned short* __restrict__ A,  // [M][K] bf16 (x rotated)
    const unsigned short* __restrict__ B,  // [N][K] bf16 (W)
    const float* __restrict__ bias, float* __restrict__ C) {
  constexpr int K = 4096, N = 4096;
  __shared__ unsigned short sA[128 * 32];
  __shared__ unsigned short sB[128 * 32];

  const int tid = threadIdx.x;
  const int lane = tid & 63;
  const int wave = tid >> 6;
  const int wr = wave >> 1;  // wave row 0..1 (64 rows each)
  const int wc = wave & 1;   // wave col 0..1 (64 cols each)
  const int row16 = lane & 15;
  const int kgrp = lane >> 4;  // 0..3

  const int m0 = blockIdx.y * 128;
  const int n0 = blockIdx.x * 128;

  // staging: 256 threads x 16B = 4096B = 64 rows x 64B; two issues per tile
  const int srow = tid >> 2;  // 0..63
  const int skc = tid & 3;    // 16B chunk within a 64B row
  const unsigned short* Ag0 = A + (size_t)(m0 + srow) * K + skc * 8;
  const unsigned short* Ag1 = Ag0 + (size_t)64 * K;
  const unsigned short* Bg0 = B + (size_t)(n0 + srow) * K + skc * 8;
  const unsigned short* Bg1 = Bg0 + (size_t)64 * K;
  unsigned short* lA0 = &sA[tid * 8];
  unsigned short* lA1 = &sA[2048 + tid * 8];
  unsigned short* lB0 = &sB[tid * 8];
  unsigned short* lB1 = &sB[2048 + tid * 8];

  f32x4 acc[4][4];
#pragma unroll
  for (int i = 0; i < 4; ++i)
#pragma unroll
    for (int j = 0; j < 4; ++j) acc[i][j] = (f32x4){0.f, 0.f, 0.f, 0.f};

  // LDS fragment read bases (A-operand layout: m = lane&15, k = kgrp*8 + j)
  const int abase = (wr * 64 + row16) * 32 + kgrp * 8;
  const int bbase = (wc * 64 + row16) * 32 + kgrp * 8;

  for (int k0 = 0; k0 < K; k0 += 32) {
    async16(Ag0 + k0, lA0);
    async16(Ag1 + k0, lA1);
    async16(Bg0 + k0, lB0);
    async16(Bg1 + k0, lB1);
    __syncthreads();  // compiler emits s_waitcnt vmcnt(0) before barrier

    bf16x8 af[4], bfr[4];
#pragma unroll
    for (int mt = 0; mt < 4; ++mt)
      af[mt] = *(const bf16x8*)&sA[abase + mt * 16 * 32];
#pragma unroll
    for (int nt = 0; nt < 4; ++nt)
      bfr[nt] = *(const bf16x8*)&sB[bbase + nt * 16 * 32];
#pragma unroll
    for (int mt = 0; mt < 4; ++mt)
#pragma unroll
      for (int nt = 0; nt < 4; ++nt)
        acc[mt][nt] = __builtin_amdgcn_mfma_f32_16x16x32_bf16(
            af[mt], bfr[nt], acc[mt][nt], 0, 0, 0);
    __syncthreads();  // protect LDS before next overwrite
  }

  // Epilogue: C/D layout col = lane&15, row = kgrp*4 + reg
  const int mbase = m0 + wr * 64 + kgrp * 4;
  const int nbase = n0 + wc * 64 + row16;
  float bv[4];
#pragma unroll
  for (int nt = 0; nt < 4; ++nt) bv[nt] = bias[nbase + nt * 16];
#pragma unroll
  for (int mt = 0; mt < 4; ++mt)
#pragma unroll
    for (int nt = 0; nt < 4; ++nt)
#pragma unroll
      for (int r = 0; r < 4; ++r)
        C[(size_t)(mbase + mt * 16 + r) * N + nbase + nt * 16] =
            acc[mt][nt][r] + bv[nt];
}

// ---------------------------------------------------------------------------
extern "C" void kernel_launch(void* const* d_in, const int* in_sizes, int n_in,
                              void* d_out, int out_size, void* d_ws,
                              size_t ws_size, hipStream_t stream) {
  const float* x = (const float*)d_in[0];    // 4*2048*4096 fp32
  const float* W = (const float*)d_in[1];    // 4096*4096 fp32
  const float* b = (const float*)d_in[2];    // 4096 fp32
  float* out = (float*)d_out;                // 8192*4096 fp32

  unsigned short* Xr = (unsigned short*)d_ws;                 // 64 MiB bf16
  unsigned short* Wb = Xr + (size_t)M_ROWS * D_DIM;           // 32 MiB bf16

  // 1) rotate x rows (WHT, normalized) -> bf16
  wht_cast_rows<<<M_ROWS, 256, 0, stream>>>(x, Xr);
  // 2) cast W -> bf16
  cast_w<<<(D_DIM * (size_t)D_DIM / 8) / 256, 256, 0, stream>>>(W, Wb);
  // 3) GEMM + bias
  dim3 grid(D_DIM / 128, M_ROWS / 128);  // (32, 64)
  gemm_bt_bias<<<grid, 256, 0, stream>>>(Xr, Wb, b, out);
}